// Round 12
// baseline (293.137 us; speedup 1.0000x reference)
//
#include <hip/hip_runtime.h>
#include <hip/hip_bf16.h>

#define DI __device__ __forceinline__

typedef __attribute__((ext_vector_type(8))) short bf16x8;
typedef __attribute__((ext_vector_type(4))) float f32x4;
typedef __attribute__((ext_vector_type(4))) _Float16 f16x4;

constexpr float LOG2E = 1.4426950408889634f;

DI float fexp(float x) { return __builtin_amdgcn_exp2f(x * LOG2E); }  // raw v_exp_f32
DI float frcp(float x) { return __builtin_amdgcn_rcpf(x); }           // raw v_rcp_f32

DI short f2bf(float f) {                 // fp32 -> bf16 via HW cvt
  __hip_bfloat16 h = __float2bfloat16(f);
  union { __hip_bfloat16 h; short s; } c; c.h = h; return c.s;
}

DI unsigned pk2(float a, float b) {      // two f32 -> packed bf16x2 (HW cvt_pk)
  union { __hip_bfloat162 h; unsigned u; } c;
  c.h.x = __float2bfloat16(a); c.h.y = __float2bfloat16(b);
  return c.u;
}

DI short f2h(float f) {                  // fp32 -> f16 bits
  _Float16 h = (_Float16)f;
  union { _Float16 h; short s; } c; c.h = h; return c.s;
}

DI f16x4 pkh4(float a, float b, float c, float d) {   // 4 f32 -> f16x4 (cvt_pkrtz)
  auto lo = __builtin_amdgcn_cvt_pkrtz(a, b);         // __fp16 ext_vector(2)
  auto hi = __builtin_amdgcn_cvt_pkrtz(c, d);
  union { struct { decltype(lo) l, h; } p; f16x4 v; } u;
  u.p.l = lo; u.p.h = hi;
  return u.v;
}

DI f16x4 ld4h(const short* p) {          // 4 f16 (8 B)
  union { uint2 u; f16x4 v; } c;
  c.u = *(const uint2*)p;
  return c.v;
}

DI f32x4 mfma16(bf16x8 a, bf16x8 b, f32x4 c) {
  // A: row=l&15, k=(l>>4)*8+j ; B: col=l&15, k=(l>>4)*8+j ; D: col=l&15, row=(l>>4)*4+reg
  return __builtin_amdgcn_mfma_f32_16x16x32_bf16(a, b, c, 0, 0, 0);
}

DI f32x4 mfmah(f16x4 a, f16x4 b, f32x4 c) {
  // 16x16x16 f16: A row=l&15, k=(l>>4)*4+j ; B col=l&15, k=(l>>4)*4+j ; D as above.
  // A/B fragment layout == D layout of the 16x16 family -> GEMM accumulators
  // convert to next-MFMA operands with an own-lane pack (no shfl, no LDS).
  return __builtin_amdgcn_mfma_f32_16x16x16f16(a, b, c, 0, 0, 0);
}

DI f32x4 fzero() { return f32x4{0.f, 0.f, 0.f, 0.f}; }

// Xs swizzled element index: row-major [64][256] bf16, XOR bits 3..5 of the
// element offset with row&7 -> b128 reads across rows hit all 32 banks.
DI int xsw(int row, int e) { return row * 256 + (e ^ ((row & 7) << 3)); }

// ---------------- K0: weights fp32 -> bf16 into ws (Wq pre-scaled) ----------------
__global__ void wconv_kernel(const float* __restrict__ a, const float* __restrict__ b,
                             const float* __restrict__ c, const float* __restrict__ d,
                             short* __restrict__ o) {
  int i = blockIdx.x * 256 + threadIdx.x;
  int mat = i >> 14;                         // block-uniform
  int off = (i & 16383) * 4;
  const float* s = (mat == 0) ? a : (mat == 1) ? b : (mat == 2) ? c : d;
  const float sc = (mat == 0) ? 0.125f : 1.0f;   // fold Ch^-0.5 into Wq
  float4 v = *(const float4*)(s + off);
  uint2 r; r.x = pk2(v.x * sc, v.y * sc); r.y = pk2(v.z * sc, v.w * sc);
  *(uint2*)(o + mat * 65536 + off) = r;
}

// ---------------- K1: FULLY FUSED QKV + softmaxes + linear attn + Wp proj ----------
// One WG = 4 consecutive pixels, 256 threads (4 waves). Each wave = one head
// for the QKV/attn phases, then one 64-out-channel slice for the Wp phase.
// Round-11 post-mortem: the pipeline total tracks whole-run HBM traffic; the
// att global round-trip (64 MB wr + 64 MB rd + k2's LDS restage + launch)
// exists only to exchange heads' channels for the Wp contraction -- but the
// block's att tile (4px x 16t x 256c bf16) is exactly 32 KB = the dead Xs
// region.  So: stage B -> att_lds (rows R = t*4 + px), barrier, per-wave Wp
// GEMM (A from swizzled att_lds, D reg index = PIXEL -> float4 stores of 4
// consecutive px; 16 B granules at the stride where r5/r11 proved L2 merges
// reads to ideal).  k2 deleted.
// Tripwire: WRITE >= 300 MB -> out write-merge failed, revert to split.
__global__ __launch_bounds__(256, 4)
void k1_kernel(const float* __restrict__ x, const short* __restrict__ wbf,
               float* __restrict__ out, short* __restrict__ qsg, int n0chunk) {
  __shared__ short SMEM[16384];       // 32768 B: Xs, then att_lds overlay
  short* Xs = SMEM;
  short* att_lds = SMEM;              // valid after barrier 2

  const int tid  = threadIdx.x;
  const int wave = tid >> 6;          // = head (QKV) / out-ch slice (Wp)
  const int lane = tid & 63;
  const int g    = lane >> 4;
  const int li   = lane & 15;

  // XCD-aware swizzle: consecutive logical bids (adjacent pixels) on same XCD
  int bid = blockIdx.x;
  const int nb = gridDim.x;
  if ((nb & 7) == 0) { const int q = nb >> 3; bid = (bid & 7) * q + (bid >> 3); }

  const int n0  = n0chunk + bid * 4;
  const int b   = n0 >> 12;
  const int hw0 = n0 & 4095;
  const float* xb = x + (size_t)b * (16 * 256 * 4096) + hw0;

  // ---- Phase 0: stage x tile -> Xs bf16 (4x4 block transpose, HW cvt_pk) ----
  {
    const int c4 = lane;                 // 4-channel block 0..63
    #pragma unroll
    for (int it = 0; it < 4; ++it) {
      const int t = it * 4 + wave;
      const float* src = xb + (size_t)(t * 256 + c4 * 4) * 4096;
      float4 v0 = *(const float4*)(src);
      float4 v1 = *(const float4*)(src + 4096);
      float4 v2 = *(const float4*)(src + 8192);
      float4 v3 = *(const float4*)(src + 12288);
      uint2 s0; s0.x = pk2(v0.x, v1.x); s0.y = pk2(v2.x, v3.x);
      uint2 s1; s1.x = pk2(v0.y, v1.y); s1.y = pk2(v2.y, v3.y);
      uint2 s2; s2.x = pk2(v0.z, v1.z); s2.y = pk2(v2.z, v3.z);
      uint2 s3; s3.x = pk2(v0.w, v1.w); s3.y = pk2(v2.w, v3.w);
      *(uint2*)&Xs[xsw(0 * 16 + t, c4 * 4)] = s0;
      *(uint2*)&Xs[xsw(1 * 16 + t, c4 * 4)] = s1;
      *(uint2*)&Xs[xsw(2 * 16 + t, c4 * 4)] = s2;
      *(uint2*)&Xs[xsw(3 * 16 + t, c4 * 4)] = s3;
    }
  }
  __syncthreads();   // barrier 1: Xs staged

  const short* wq = wbf;
  const short* wk = wbf + 65536;
  const short* wv = wbf + 131072;
  const size_t wrow = (size_t)(wave * 64) * 256;
  // per (px, head) q_soft tile: 16 t x 64 c f16 = 1024 shorts
  short* qsw = qsg + ((size_t)bid * 4 * 4 + wave) * 1024;

  // ---- Pass Q FIRST (all 4 px; scale pre-folded into wq) ----
  {
    f32x4 qacc[4][4];
    #pragma unroll
    for (int p = 0; p < 4; ++p)
      #pragma unroll
      for (int nt = 0; nt < 4; ++nt) qacc[p][nt] = fzero();

    __builtin_amdgcn_s_setprio(1);
    #pragma unroll
    for (int ks = 0; ks < 8; ++ks) {
      bf16x8 qb[4];
      #pragma unroll
      for (int nt = 0; nt < 4; ++nt)
        qb[nt] = *(const bf16x8*)(wq + wrow + (size_t)(nt * 16 + li) * 256 + ks * 32 + g * 8);
      #pragma unroll
      for (int p = 0; p < 4; ++p) {
        bf16x8 af = *(const bf16x8*)&Xs[xsw(p * 16 + li, ks * 32 + g * 8)];
        #pragma unroll
        for (int nt = 0; nt < 4; ++nt)
          qacc[p][nt] = mfma16(af, qb[nt], qacc[p][nt]);
      }
    }
    __builtin_amdgcn_s_setprio(0);

    // Q softmax over c (64 per head), no max-sub -> normalized f16 to qsg
    #pragma unroll
    for (int p = 0; p < 4; ++p) {
      short* qsp = qsw + p * 4096;     // px stride = 4 heads * 1024
      #pragma unroll
      for (int r = 0; r < 4; ++r) {
        float e0 = fexp(qacc[p][0][r]);
        float e1 = fexp(qacc[p][1][r]);
        float e2 = fexp(qacc[p][2][r]);
        float e3 = fexp(qacc[p][3][r]);
        float s = e0 + e1 + e2 + e3;
        s += __shfl_xor(s, 1); s += __shfl_xor(s, 2);
        s += __shfl_xor(s, 4); s += __shfl_xor(s, 8);
        const float inv = frcp(s);
        const int t = g * 4 + r;
        short* dst = qsp + t * 64 + li;
        dst[0]  = f2h(e0 * inv);
        dst[16] = f2h(e1 * inv);
        dst[32] = f2h(e2 * inv);
        dst[48] = f2h(e3 * inv);
      }
    }
  }

  // ---- Pass K (all 4 px) -> t-softmax -> own-lane f16 A-frags ----
  f16x4 akf[4][4];
  {
    f32x4 kacc[4][4];
    #pragma unroll
    for (int p = 0; p < 4; ++p)
      #pragma unroll
      for (int nt = 0; nt < 4; ++nt) kacc[p][nt] = fzero();

    __builtin_amdgcn_s_setprio(1);
    #pragma unroll
    for (int ks = 0; ks < 8; ++ks) {
      bf16x8 kb[4];
      #pragma unroll
      for (int nt = 0; nt < 4; ++nt)
        kb[nt] = *(const bf16x8*)(wk + wrow + (size_t)(nt * 16 + li) * 256 + ks * 32 + g * 8);
      #pragma unroll
      for (int p = 0; p < 4; ++p) {
        bf16x8 af = *(const bf16x8*)&Xs[xsw(p * 16 + li, ks * 32 + g * 8)];
        #pragma unroll
        for (int nt = 0; nt < 4; ++nt)
          kacc[p][nt] = mfma16(af, kb[nt], kacc[p][nt]);
      }
    }
    __builtin_amdgcn_s_setprio(0);

    // softmax over t (4 regs + g-groups), no max-sub (scores ~ N(0,1))
    #pragma unroll
    for (int p = 0; p < 4; ++p)
      #pragma unroll
      for (int nt = 0; nt < 4; ++nt) {
        float e0 = fexp(kacc[p][nt][0]);
        float e1 = fexp(kacc[p][nt][1]);
        float e2 = fexp(kacc[p][nt][2]);
        float e3 = fexp(kacc[p][nt][3]);
        float s = e0 + e1 + e2 + e3;
        s += __shfl_xor(s, 16);
        s += __shfl_xor(s, 32);
        const float inv = frcp(s);
        akf[p][nt] = pkh4(e0 * inv, e1 * inv, e2 * inv, e3 * inv);
      }
  }

  // ---- Pass V (two nt-halves; vacc[4][2] live) -> own-lane f16 B-frags ----
  f16x4 bvf[4][4];
  #pragma unroll
  for (int h = 0; h < 2; ++h) {
    f32x4 vacc[4][2];
    #pragma unroll
    for (int p = 0; p < 4; ++p)
      #pragma unroll
      for (int n2 = 0; n2 < 2; ++n2) vacc[p][n2] = fzero();

    __builtin_amdgcn_s_setprio(1);
    #pragma unroll
    for (int ks = 0; ks < 8; ++ks) {
      bf16x8 vb[2];
      #pragma unroll
      for (int n2 = 0; n2 < 2; ++n2)
        vb[n2] = *(const bf16x8*)(wv + wrow + (size_t)((h * 2 + n2) * 16 + li) * 256 + ks * 32 + g * 8);
      #pragma unroll
      for (int p = 0; p < 4; ++p) {
        bf16x8 af = *(const bf16x8*)&Xs[xsw(p * 16 + li, ks * 32 + g * 8)];
        #pragma unroll
        for (int n2 = 0; n2 < 2; ++n2)
          vacc[p][n2] = mfma16(af, vb[n2], vacc[p][n2]);
      }
    }
    __builtin_amdgcn_s_setprio(0);

    #pragma unroll
    for (int p = 0; p < 4; ++p)
      #pragma unroll
      for (int n2 = 0; n2 < 2; ++n2)
        bvf[p][h * 2 + n2] = pkh4(vacc[p][n2][0], vacc[p][n2][1],
                                  vacc[p][n2][2], vacc[p][n2][3]);
  }

  // retire this wave's qsg stores (readback below), then free Xs for att_lds
  asm volatile("s_waitcnt vmcnt(0)" ::: "memory");
  __syncthreads();   // barrier 2: all waves done with Xs -> overlay att_lds

  // ---- Per-pixel stage B: kv (16x16x16 f16) pure-register; att -> LDS ----
  // att_lds rows R = t*4 + px  (so the Wp GEMM's D reg index == pixel)
  #pragma unroll
  for (int p = 0; p < 4; ++p) {
    const short* qsp = qsw + p * 4096;
    f32x4 oacc[4];
    #pragma unroll
    for (int nt = 0; nt < 4; ++nt) oacc[nt] = fzero();

    #pragma unroll
    for (int cq = 0; cq < 4; ++cq) {        // c-chunks of 16
      // kv chunk: kva[nt] lane holds kv[c=cq*16+g*4+r][d=nt*16+li]
      f32x4 kva[4];
      #pragma unroll
      for (int nt = 0; nt < 4; ++nt)
        kva[nt] = mfmah(akf[p][cq], bvf[p][nt], fzero());
      // aq: A-frag q_soft[t=li][c=cq*16+g*4+j] from qsg (L2-hot)
      f16x4 aq = ld4h(qsp + li * 64 + cq * 16 + g * 4);
      // kva IS the mfmah B-frag (k=g*4+j, n=li) -> own-lane pack, no transpose
      #pragma unroll
      for (int nt = 0; nt < 4; ++nt) {
        f16x4 kb16 = pkh4(kva[nt][0], kva[nt][1], kva[nt][2], kva[nt][3]);
        oacc[nt] = mfmah(aq, kb16, oacc[nt]);
      }
    }

    // oacc D-layout: c = nt*16+li, t = g*4+r  ->  att_lds[(t*4+p)][c]
    #pragma unroll
    for (int nt = 0; nt < 4; ++nt)
      #pragma unroll
      for (int r = 0; r < 4; ++r) {
        const int row = (g * 4 + r) * 4 + p;
        att_lds[xsw(row, wave * 64 + nt * 16 + li)] = f2bf(oacc[nt][r]);
      }
  }

  __syncthreads();   // barrier 3: att_lds complete

  // ---- Fused Wp GEMM: out[t][c_out][px] for this wave's 64 c_out slice ----
  {
    const short* wp = wbf + 3 * 65536;
    f32x4 pacc[4][4];   // [mt(row-tile)][n4(col-tile)]
    #pragma unroll
    for (int mt = 0; mt < 4; ++mt)
      #pragma unroll
      for (int n4 = 0; n4 < 4; ++n4) pacc[mt][n4] = fzero();

    __builtin_amdgcn_s_setprio(1);
    #pragma unroll
    for (int ks = 0; ks < 8; ++ks) {
      bf16x8 bw[4];
      #pragma unroll
      for (int n4 = 0; n4 < 4; ++n4)
        bw[n4] = *(const bf16x8*)(wp + (size_t)((wave * 4 + n4) * 16 + li) * 256 + ks * 32 + g * 8);
      #pragma unroll
      for (int mt = 0; mt < 4; ++mt) {
        bf16x8 af = *(const bf16x8*)&att_lds[xsw(mt * 16 + li, ks * 32 + g * 8)];
        #pragma unroll
        for (int n4 = 0; n4 < 4; ++n4)
          pacc[mt][n4] = mfma16(af, bw[n4], pacc[mt][n4]);
      }
    }
    __builtin_amdgcn_s_setprio(0);

    // D: col = c_out = (wave*4+n4)*16+li ; row = g*4+reg = (t_local)*4+px
    // -> t = mt*4 + g, px = reg: float4 = 4 consecutive pixels (16 B)
    float* ob = out + (size_t)b * (16 * 256 * 4096) + hw0;
    #pragma unroll
    for (int mt = 0; mt < 4; ++mt)
      #pragma unroll
      for (int n4 = 0; n4 < 4; ++n4) {
        const int t = mt * 4 + g;
        const int c = (wave * 4 + n4) * 16 + li;
        float4 v;
        v.x = pacc[mt][n4][0]; v.y = pacc[mt][n4][1];
        v.z = pacc[mt][n4][2]; v.w = pacc[mt][n4][3];
        *(float4*)(ob + (size_t)(t * 256 + c) * 4096) = v;
      }
  }
}

extern "C" void kernel_launch(void* const* d_in, const int* in_sizes, int n_in,
                              void* d_out, int out_size, void* d_ws, size_t ws_size,
                              hipStream_t stream) {
  const float* x  = (const float*)d_in[0];
  const float* Wq = (const float*)d_in[1];
  const float* Wk = (const float*)d_in[2];
  const float* Wv = (const float*)d_in[3];
  const float* Wp = (const float*)d_in[4];
  float* out = (float*)d_out;

  short* wbf = (short*)d_ws;          // 4 x 65536 bf16 = 512 KB
  short* qsg = wbf + 4 * 65536;       // q_soft scratch (f16), chunked

  wconv_kernel<<<256, 256, 0, stream>>>(Wq, Wk, Wv, Wp, wbf);

  const size_t wsAvail = (ws_size > 524288) ? (ws_size - 524288) : 0;
  const size_t perPix = 16 * 256 * 2;  // 8 KB per pixel for qsg
  int chunk = 16;
  while (chunk < 8192 && (size_t)(chunk * 1) * perPix <= wsAvail) chunk <<= 1;

  for (int n0 = 0; n0 < 8192; n0 += chunk) {
    k1_kernel<<<chunk / 4, 256, 0, stream>>>(x, wbf, out, qsg, n0);
  }
}

// Round 13
// 251.584 us; speedup vs baseline: 1.1652x; 1.1652x over previous
//
#include <hip/hip_runtime.h>
#include <hip/hip_bf16.h>

#define DI __device__ __forceinline__

typedef __attribute__((ext_vector_type(8))) short bf16x8;
typedef __attribute__((ext_vector_type(4))) float f32x4;
typedef __attribute__((ext_vector_type(4))) _Float16 f16x4;

constexpr float LOG2E = 1.4426950408889634f;

DI float fexp(float x) { return __builtin_amdgcn_exp2f(x * LOG2E); }  // raw v_exp_f32
DI float frcp(float x) { return __builtin_amdgcn_rcpf(x); }           // raw v_rcp_f32

DI short f2bf(float f) {                 // fp32 -> bf16 via HW cvt
  __hip_bfloat16 h = __float2bfloat16(f);
  union { __hip_bfloat16 h; short s; } c; c.h = h; return c.s;
}

DI unsigned pk2(float a, float b) {      // two f32 -> packed bf16x2 (HW cvt_pk)
  union { __hip_bfloat162 h; unsigned u; } c;
  c.h.x = __float2bfloat16(a); c.h.y = __float2bfloat16(b);
  return c.u;
}

DI short f2h(float f) {                  // fp32 -> f16 bits
  _Float16 h = (_Float16)f;
  union { _Float16 h; short s; } c; c.h = h; return c.s;
}

DI f16x4 pkh4(float a, float b, float c, float d) {   // 4 f32 -> f16x4 (cvt_pkrtz)
  auto lo = __builtin_amdgcn_cvt_pkrtz(a, b);         // __fp16 ext_vector(2)
  auto hi = __builtin_amdgcn_cvt_pkrtz(c, d);
  union { struct { decltype(lo) l, h; } p; f16x4 v; } u;
  u.p.l = lo; u.p.h = hi;
  return u.v;
}

DI f16x4 ld4h(const short* p) {          // 4 f16 (8 B)
  union { uint2 u; f16x4 v; } c;
  c.u = *(const uint2*)p;
  return c.v;
}

DI f32x4 mfma16(bf16x8 a, bf16x8 b, f32x4 c) {
  // A: row=l&15, k=(l>>4)*8+j ; B: col=l&15, k=(l>>4)*8+j ; D: col=l&15, row=(l>>4)*4+reg
  return __builtin_amdgcn_mfma_f32_16x16x32_bf16(a, b, c, 0, 0, 0);
}

DI f32x4 mfmah(f16x4 a, f16x4 b, f32x4 c) {
  // 16x16x16 f16: A row=l&15, k=(l>>4)*4+j ; B col=l&15, k=(l>>4)*4+j ; D as above.
  // A/B fragment layout == D layout of the 16x16 family -> GEMM accumulators
  // convert to next-MFMA operands with an own-lane pack (no shfl, no LDS).
  return __builtin_amdgcn_mfma_f32_16x16x16f16(a, b, c, 0, 0, 0);
}

DI f32x4 fzero() { return f32x4{0.f, 0.f, 0.f, 0.f}; }

// Swizzled element index: row-major [R][256] bf16, XOR bits 3..5 of the
// element offset with row&7 -> b128 reads across rows hit all 32 banks.
DI int xsw(int row, int e) { return row * 256 + (e ^ ((row & 7) << 3)); }

// ---------------- K0: weights fp32 -> bf16 into ws (Wq pre-scaled) ----------------
__global__ void wconv_kernel(const float* __restrict__ a, const float* __restrict__ b,
                             const float* __restrict__ c, const float* __restrict__ d,
                             short* __restrict__ o) {
  int i = blockIdx.x * 256 + threadIdx.x;
  int mat = i >> 14;                         // block-uniform
  int off = (i & 16383) * 4;
  const float* s = (mat == 0) ? a : (mat == 1) ? b : (mat == 2) ? c : d;
  const float sc = (mat == 0) ? 0.125f : 1.0f;   // fold Ch^-0.5 into Wq
  float4 v = *(const float4*)(s + off);
  uint2 r; r.x = pk2(v.x * sc, v.y * sc); r.y = pk2(v.z * sc, v.w * sc);
  *(uint2*)(o + mat * 65536 + off) = r;
}

// ---------------- K1: FULLY FUSED, 16-pixel mega-block ----------------
// Round-12 post-mortem: fused-k2 writes were 16 B partial lines (block owned
// 4 px; an out cache line spans 16 px) -> 3.3x write amplification (439 MB).
// Fix: block = 16 px, 1024 threads (16 waves), 128 KB LDS (gfx950 allows
// 160 KB/WG).  Wave = (head, px-quad): QKV/attn phases are r11's per-wave
// content verbatim (4 px/wave, VGPR 64 measured, same weight amortization).
// Xs = [px*16+t][256c] (128 KB), overlaid by att_lds [t*16+px][256c] after
// pass V.  Wp phase: wave (mb,nb) tile of the 256x256 GEMM; A-row low index
// = px -> D px = g*4+reg -> float4 stores at +g*4 assemble FULL 64-B lines
// (k2's proven store pattern).  Phase-0 x reads are full-line coalesced too.
// Occupancy: 1 block/CU x 16 waves = 4 waves/SIMD (= r11's level).
// Tripwires: WRITE > 250 MB -> write path broken; dur > 242 -> revert r11.
__global__ __launch_bounds__(1024, 4)
void k1_kernel(const float* __restrict__ x, const short* __restrict__ wbf,
               float* __restrict__ out, short* __restrict__ qsg, int n0chunk) {
  __shared__ short SMEM[65536];       // 131072 B: Xs, then att_lds overlay
  short* Xs = SMEM;
  short* att_lds = SMEM;              // valid after barrier 2

  const int tid  = threadIdx.x;
  const int wv   = tid >> 6;          // 0..15
  const int lane = tid & 63;
  const int g    = lane >> 4;
  const int li   = lane & 15;
  const int head = wv & 3;            // QKV phase: head
  const int quad = wv >> 2;           // QKV phase: pixel quad (px = quad*4+p)

  // XCD-aware swizzle: consecutive logical bids on same XCD
  int bid = blockIdx.x;
  const int nb = gridDim.x;
  if ((nb & 7) == 0) { const int q = nb >> 3; bid = (bid & 7) * q + (bid >> 3); }

  const int n0  = n0chunk + bid * 16;
  const int b   = n0 >> 12;
  const int hw0 = n0 & 4095;
  const float* xb = x + (size_t)b * (16 * 256 * 4096) + hw0;

  // ---- Phase 0: stage x tile -> Xs bf16 (full-line reads, 4x4 transpose) ----
  // 4096 jobs: (t, c-quad, px-quad).  4 lanes x 16 B = 64 B line per (t,c).
  {
    #pragma unroll
    for (int it = 0; it < 4; ++it) {
      const int idx = it * 1024 + tid;
      const int pq  = idx & 3;                 // px-quad
      const int cq  = (idx >> 2) & 63;         // c-quad
      const int t   = idx >> 8;                // 0..15
      const float* src = xb + (size_t)(t * 256 + cq * 4) * 4096 + pq * 4;
      float4 v0 = *(const float4*)(src);               // c+0, px pq*4..+3
      float4 v1 = *(const float4*)(src + 4096);        // c+1
      float4 v2 = *(const float4*)(src + 8192);        // c+2
      float4 v3 = *(const float4*)(src + 12288);       // c+3
      uint2 s0; s0.x = pk2(v0.x, v1.x); s0.y = pk2(v2.x, v3.x);
      uint2 s1; s1.x = pk2(v0.y, v1.y); s1.y = pk2(v2.y, v3.y);
      uint2 s2; s2.x = pk2(v0.z, v1.z); s2.y = pk2(v2.z, v3.z);
      uint2 s3; s3.x = pk2(v0.w, v1.w); s3.y = pk2(v2.w, v3.w);
      *(uint2*)&Xs[xsw((pq * 4 + 0) * 16 + t, cq * 4)] = s0;
      *(uint2*)&Xs[xsw((pq * 4 + 1) * 16 + t, cq * 4)] = s1;
      *(uint2*)&Xs[xsw((pq * 4 + 2) * 16 + t, cq * 4)] = s2;
      *(uint2*)&Xs[xsw((pq * 4 + 3) * 16 + t, cq * 4)] = s3;
    }
  }
  __syncthreads();   // barrier 1: Xs staged

  const short* wq = wbf;
  const short* wk = wbf + 65536;
  const short* wv_ = wbf + 131072;
  const size_t wrow = (size_t)(head * 64) * 256;
  // per (px, head) q_soft tile: 16 t x 64 c f16 = 1024 shorts
  short* qsw = qsg + ((size_t)(bid * 16 + quad * 4) * 4 + head) * 1024;

  // ---- Pass Q FIRST (4 px of this quad; scale pre-folded into wq) ----
  {
    f32x4 qacc[4][4];
    #pragma unroll
    for (int p = 0; p < 4; ++p)
      #pragma unroll
      for (int nt = 0; nt < 4; ++nt) qacc[p][nt] = fzero();

    __builtin_amdgcn_s_setprio(1);
    #pragma unroll
    for (int ks = 0; ks < 8; ++ks) {
      bf16x8 qb[4];
      #pragma unroll
      for (int nt = 0; nt < 4; ++nt)
        qb[nt] = *(const bf16x8*)(wq + wrow + (size_t)(nt * 16 + li) * 256 + ks * 32 + g * 8);
      #pragma unroll
      for (int p = 0; p < 4; ++p) {
        bf16x8 af = *(const bf16x8*)&Xs[xsw((quad * 4 + p) * 16 + li, ks * 32 + g * 8)];
        #pragma unroll
        for (int nt = 0; nt < 4; ++nt)
          qacc[p][nt] = mfma16(af, qb[nt], qacc[p][nt]);
      }
    }
    __builtin_amdgcn_s_setprio(0);

    // Q softmax over c (64 per head), no max-sub -> normalized f16 to qsg
    #pragma unroll
    for (int p = 0; p < 4; ++p) {
      short* qsp = qsw + p * 4096;     // px stride = 4 heads * 1024
      #pragma unroll
      for (int r = 0; r < 4; ++r) {
        float e0 = fexp(qacc[p][0][r]);
        float e1 = fexp(qacc[p][1][r]);
        float e2 = fexp(qacc[p][2][r]);
        float e3 = fexp(qacc[p][3][r]);
        float s = e0 + e1 + e2 + e3;
        s += __shfl_xor(s, 1); s += __shfl_xor(s, 2);
        s += __shfl_xor(s, 4); s += __shfl_xor(s, 8);
        const float inv = frcp(s);
        const int t = g * 4 + r;
        short* dst = qsp + t * 64 + li;
        dst[0]  = f2h(e0 * inv);
        dst[16] = f2h(e1 * inv);
        dst[32] = f2h(e2 * inv);
        dst[48] = f2h(e3 * inv);
      }
    }
  }

  // ---- Pass K (4 px) -> t-softmax -> own-lane f16 A-frags ----
  f16x4 akf[4][4];
  {
    f32x4 kacc[4][4];
    #pragma unroll
    for (int p = 0; p < 4; ++p)
      #pragma unroll
      for (int nt = 0; nt < 4; ++nt) kacc[p][nt] = fzero();

    __builtin_amdgcn_s_setprio(1);
    #pragma unroll
    for (int ks = 0; ks < 8; ++ks) {
      bf16x8 kb[4];
      #pragma unroll
      for (int nt = 0; nt < 4; ++nt)
        kb[nt] = *(const bf16x8*)(wk + wrow + (size_t)(nt * 16 + li) * 256 + ks * 32 + g * 8);
      #pragma unroll
      for (int p = 0; p < 4; ++p) {
        bf16x8 af = *(const bf16x8*)&Xs[xsw((quad * 4 + p) * 16 + li, ks * 32 + g * 8)];
        #pragma unroll
        for (int nt = 0; nt < 4; ++nt)
          kacc[p][nt] = mfma16(af, kb[nt], kacc[p][nt]);
      }
    }
    __builtin_amdgcn_s_setprio(0);

    // softmax over t (4 regs + g-groups), no max-sub (scores ~ N(0,1))
    #pragma unroll
    for (int p = 0; p < 4; ++p)
      #pragma unroll
      for (int nt = 0; nt < 4; ++nt) {
        float e0 = fexp(kacc[p][nt][0]);
        float e1 = fexp(kacc[p][nt][1]);
        float e2 = fexp(kacc[p][nt][2]);
        float e3 = fexp(kacc[p][nt][3]);
        float s = e0 + e1 + e2 + e3;
        s += __shfl_xor(s, 16);
        s += __shfl_xor(s, 32);
        const float inv = frcp(s);
        akf[p][nt] = pkh4(e0 * inv, e1 * inv, e2 * inv, e3 * inv);
      }
  }

  // ---- Pass V (two nt-halves; vacc[4][2] live) -> own-lane f16 B-frags ----
  f16x4 bvf[4][4];
  #pragma unroll
  for (int h = 0; h < 2; ++h) {
    f32x4 vacc[4][2];
    #pragma unroll
    for (int p = 0; p < 4; ++p)
      #pragma unroll
      for (int n2 = 0; n2 < 2; ++n2) vacc[p][n2] = fzero();

    __builtin_amdgcn_s_setprio(1);
    #pragma unroll
    for (int ks = 0; ks < 8; ++ks) {
      bf16x8 vb[2];
      #pragma unroll
      for (int n2 = 0; n2 < 2; ++n2)
        vb[n2] = *(const bf16x8*)(wv_ + wrow + (size_t)((h * 2 + n2) * 16 + li) * 256 + ks * 32 + g * 8);
      #pragma unroll
      for (int p = 0; p < 4; ++p) {
        bf16x8 af = *(const bf16x8*)&Xs[xsw((quad * 4 + p) * 16 + li, ks * 32 + g * 8)];
        #pragma unroll
        for (int n2 = 0; n2 < 2; ++n2)
          vacc[p][n2] = mfma16(af, vb[n2], vacc[p][n2]);
      }
    }
    __builtin_amdgcn_s_setprio(0);

    #pragma unroll
    for (int p = 0; p < 4; ++p)
      #pragma unroll
      for (int n2 = 0; n2 < 2; ++n2)
        bvf[p][h * 2 + n2] = pkh4(vacc[p][n2][0], vacc[p][n2][1],
                                  vacc[p][n2][2], vacc[p][n2][3]);
  }

  __syncthreads();   // barrier 2: Xs dead; drains this wave's qsg stores too

  // ---- Stage B: kv (16x16x16 f16) pure-register; att -> att_lds ----
  // att_lds rows R = t*16 + px  (so Wp's D reg/g indices == pixel)
  #pragma unroll
  for (int p = 0; p < 4; ++p) {
    const short* qsp = qsw + p * 4096;
    const int px = quad * 4 + p;
    f32x4 oacc[4];
    #pragma unroll
    for (int nt = 0; nt < 4; ++nt) oacc[nt] = fzero();

    #pragma unroll
    for (int cq = 0; cq < 4; ++cq) {        // c-chunks of 16
      f32x4 kva[4];
      #pragma unroll
      for (int nt = 0; nt < 4; ++nt)
        kva[nt] = mfmah(akf[p][cq], bvf[p][nt], fzero());
      f16x4 aq = ld4h(qsp + li * 64 + cq * 16 + g * 4);
      #pragma unroll
      for (int nt = 0; nt < 4; ++nt) {
        f16x4 kb16 = pkh4(kva[nt][0], kva[nt][1], kva[nt][2], kva[nt][3]);
        oacc[nt] = mfmah(aq, kb16, oacc[nt]);
      }
    }

    // oacc D-layout: c = nt*16+li, t = g*4+r  ->  att_lds[t*16+px][head*64+c]
    #pragma unroll
    for (int nt = 0; nt < 4; ++nt)
      #pragma unroll
      for (int r = 0; r < 4; ++r) {
        const int row = (g * 4 + r) * 16 + px;
        att_lds[xsw(row, head * 64 + nt * 16 + li)] = f2bf(oacc[nt][r]);
      }
  }

  __syncthreads();   // barrier 3: att_lds complete

  // ---- Fused Wp GEMM (256x256x256): wave = (mb = wv>>2, nb = wv&3) ----
  {
    const short* wp = wbf + 3 * 65536;
    const int mb = wv >> 2;             // t-block (4 t per mb)
    const int nbt = wv & 3;             // c_out block (64 per nbt)
    f32x4 pacc[4][4];                   // [mt][n4]
    #pragma unroll
    for (int mt = 0; mt < 4; ++mt)
      #pragma unroll
      for (int n4 = 0; n4 < 4; ++n4) pacc[mt][n4] = fzero();

    __builtin_amdgcn_s_setprio(1);
    #pragma unroll
    for (int ks = 0; ks < 8; ++ks) {
      bf16x8 bw[4];
      #pragma unroll
      for (int n4 = 0; n4 < 4; ++n4)
        bw[n4] = *(const bf16x8*)(wp + (size_t)((nbt * 64 + n4 * 16 + li)) * 256 + ks * 32 + g * 8);
      #pragma unroll
      for (int mt = 0; mt < 4; ++mt) {
        // A row R = mb*64 + mt*16 + li -> t = mb*4+mt, px = li
        bf16x8 af = *(const bf16x8*)&att_lds[xsw(mb * 64 + mt * 16 + li, ks * 32 + g * 8)];
        #pragma unroll
        for (int n4 = 0; n4 < 4; ++n4)
          pacc[mt][n4] = mfma16(af, bw[n4], pacc[mt][n4]);
      }
    }
    __builtin_amdgcn_s_setprio(0);

    // D: col = c_out = nbt*64 + n4*16 + li ; row = g*4+reg = px
    // -> float4 at +g*4 covers px g*4..g*4+3; 4 g-groups = full 64-B line
    float* ob = out + (size_t)b * (16 * 256 * 4096) + hw0;
    #pragma unroll
    for (int mt = 0; mt < 4; ++mt)
      #pragma unroll
      for (int n4 = 0; n4 < 4; ++n4) {
        const int t = mb * 4 + mt;
        const int c = nbt * 64 + n4 * 16 + li;
        float4 v;
        v.x = pacc[mt][n4][0]; v.y = pacc[mt][n4][1];
        v.z = pacc[mt][n4][2]; v.w = pacc[mt][n4][3];
        *(float4*)(ob + (size_t)(t * 256 + c) * 4096 + g * 4) = v;
      }
  }
}

extern "C" void kernel_launch(void* const* d_in, const int* in_sizes, int n_in,
                              void* d_out, int out_size, void* d_ws, size_t ws_size,
                              hipStream_t stream) {
  const float* x  = (const float*)d_in[0];
  const float* Wq = (const float*)d_in[1];
  const float* Wk = (const float*)d_in[2];
  const float* Wv = (const float*)d_in[3];
  const float* Wp = (const float*)d_in[4];
  float* out = (float*)d_out;

  short* wbf = (short*)d_ws;          // 4 x 65536 bf16 = 512 KB
  short* qsg = wbf + 4 * 65536;       // q_soft scratch (f16), chunked

  wconv_kernel<<<256, 256, 0, stream>>>(Wq, Wk, Wv, Wp, wbf);

  const size_t wsAvail = (ws_size > 524288) ? (ws_size - 524288) : 0;
  const size_t perPix = 16 * 256 * 2;  // 8 KB per pixel for qsg
  int chunk = 16;
  while (chunk < 8192 && (size_t)(chunk * 1) * perPix <= wsAvail) chunk <<= 1;

  for (int n0 = 0; n0 < 8192; n0 += chunk) {
    k1_kernel<<<chunk / 16, 1024, 0, stream>>>(x, wbf, out, qsg, n0);
  }
}